// Round 3
// baseline (2941.186 us; speedup 1.0000x reference)
//
#include <hip/hip_runtime.h>
#include <hip/hip_bf16.h>

// out[b,n,f] = sum_{l,m} cg[l,m,n] * x1[b,l,f] * x2[b,m,f]
// B=20000, P=1, L=16, LOUT=49 (padded 64), F=512
// Per-b GEMM  OUT[64,512] = CG^T[64,256] (bf16, const) * O[256,512],
// O[l*16+m, f] = x1[l,f]*x2[m,f] built on the fly in registers.
// Epilogue goes through LDS so HBM writes are fully coalesced float4 streams.

#define TP_L    16
#define TP_K    256   // 16*16
#define TP_NOUT 49
#define TP_NPAD 64
#define TP_F    512

typedef short short8 __attribute__((ext_vector_type(8)));
typedef float f32x4  __attribute__((ext_vector_type(4)));

static __device__ __forceinline__ short f2bf(float f) {
    unsigned u = __float_as_uint(f);
    u += 0x7fffu + ((u >> 16) & 1u);
    return (short)(u >> 16);
}

__global__ void prep_cg_kernel(const float* __restrict__ cg, short* __restrict__ cgT) {
    int idx = blockIdx.x * 256 + threadIdx.x;   // 0 .. 64*256-1
    int n = idx >> 8;
    int k = idx & 255;
    float v = (n < TP_NOUT) ? cg[k * TP_NOUT + n] : 0.0f;
    cgT[idx] = f2bf(v);
}

__global__ void __launch_bounds__(512, 4) tp_kernel(
    const float* __restrict__ x1, const float* __restrict__ x2,
    const short* __restrict__ cgT, float* __restrict__ out)
{
    __shared__ float smem[16384];               // 64 KB, reused for output staging
    float* sx1 = smem;                          // 16x512 fp32
    float* sx2 = smem + 8192;

    const int b   = blockIdx.x;
    const int tid = threadIdx.x;

    // ---- stage x1[b], x2[b] into LDS, 16B-coalesced ----
    const f32x4* g1 = (const f32x4*)(x1 + (size_t)b * (TP_L * TP_F));
    const f32x4* g2 = (const f32x4*)(x2 + (size_t)b * (TP_L * TP_F));
#pragma unroll
    for (int i = 0; i < 4; ++i) {
        ((f32x4*)sx1)[tid + i * 512] = g1[tid + i * 512];
        ((f32x4*)sx2)[tid + i * 512] = g2[tid + i * 512];
    }
    __syncthreads();

    const int lane = tid & 63;
    const int w    = tid >> 6;      // wave 0..7 -> f range [w*64, w*64+64)
    const int fl   = lane & 15;     // f within 16-tile; also A-row within n-tile
    const int g    = lane >> 4;     // quarter-wave 0..3
    const int hg   = g >> 1;        // which l within the k-step pair
    const int qg   = g & 1;         // which m-octet
    const int fb   = w * 64;

    f32x4 acc[4][4];                // [n-tile][f-tile]
#pragma unroll
    for (int nt = 0; nt < 4; ++nt)
#pragma unroll
        for (int ft = 0; ft < 4; ++ft)
            acc[nt][ft] = (f32x4){0.f, 0.f, 0.f, 0.f};

    // K loop: 8 steps of K=32.  k = 32s + 8g + i  ->  l = 2s+hg, m = 8*qg+i
#pragma unroll
    for (int s = 0; s < 8; ++s) {
        short8 a[4];
#pragma unroll
        for (int nt = 0; nt < 4; ++nt) {
            a[nt] = *(const short8*)(cgT + (nt * 16 + fl) * TP_K + s * 32 + g * 8);
        }
#pragma unroll
        for (int ft = 0; ft < 4; ++ft) {
            const int f = fb + ft * 16 + fl;
            const float x1v = sx1[(2 * s + hg) * TP_F + f];
            const float* x2c = &sx2[(qg * 8) * TP_F + f];
            short8 bfr;
#pragma unroll
            for (int i = 0; i < 8; ++i) {
                bfr[i] = f2bf(x1v * x2c[i * TP_F]);
            }
#pragma unroll
            for (int nt = 0; nt < 4; ++nt) {
                acc[nt][ft] = __builtin_amdgcn_mfma_f32_16x16x32_bf16(
                    a[nt], bfr, acc[nt][ft], 0, 0, 0);
            }
        }
    }

    // ---- epilogue via LDS: coalesced f32x4 streaming stores ----
    // acc[nt][ft][j] = OUT[n = nt*16 + g*4 + j][f = fb + ft*16 + fl]
    float* outb = out + (size_t)b * (TP_NOUT * TP_F);

    __syncthreads();   // everyone done reading sx1/sx2

    // pass 0: n in [0,32)  -> 32*512 floats = 64 KB staged
#pragma unroll
    for (int nt = 0; nt < 2; ++nt) {
#pragma unroll
        for (int j = 0; j < 4; ++j) {
            const int n = nt * 16 + g * 4 + j;
#pragma unroll
            for (int ft = 0; ft < 4; ++ft)
                smem[n * TP_F + fb + ft * 16 + fl] = acc[nt][ft][j];
        }
    }
    __syncthreads();
#pragma unroll
    for (int it = 0; it < 8; ++it) {
        const int idx = it * 512 + tid;
        f32x4 v = ((const f32x4*)smem)[idx];
        __builtin_nontemporal_store(v, (f32x4*)outb + idx);
    }
    __syncthreads();   // done reading staged pass-0 data

    // pass 1: n in [32,49) -> 17*512 floats = 34 KB staged
#pragma unroll
    for (int j = 0; j < 4; ++j) {
        const int n = 32 + g * 4 + j;     // 32..47  (nt=2)
#pragma unroll
        for (int ft = 0; ft < 4; ++ft)
            smem[(n - 32) * TP_F + fb + ft * 16 + fl] = acc[2][ft][j];
    }
    if (g == 0) {                         // nt=3: only n=48 valid (j=0)
#pragma unroll
        for (int ft = 0; ft < 4; ++ft)
            smem[16 * TP_F + fb + ft * 16 + fl] = acc[3][ft][0];
    }
    __syncthreads();
    const int nv1 = 17 * TP_F / 4;        // 2176 f32x4
#pragma unroll
    for (int it = 0; it < 5; ++it) {
        const int idx = it * 512 + tid;
        if (idx < nv1) {
            f32x4 v = ((const f32x4*)smem)[idx];
            __builtin_nontemporal_store(v, (f32x4*)(outb + 32 * TP_F) + idx);
        }
    }
}

extern "C" void kernel_launch(void* const* d_in, const int* in_sizes, int n_in,
                              void* d_out, int out_size, void* d_ws, size_t ws_size,
                              hipStream_t stream) {
    const float* x1 = (const float*)d_in[0];
    const float* x2 = (const float*)d_in[1];
    const float* cg = (const float*)d_in[2];
    float* out = (float*)d_out;
    short* cgT = (short*)d_ws;   // 64*256*2 = 32 KB scratch

    const int B = in_sizes[0] / (TP_L * TP_F);

    prep_cg_kernel<<<TP_NPAD, 256, 0, stream>>>(cg, cgT);
    tp_kernel<<<B, 512, 0, stream>>>(x1, x2, cgT, out);
}